// Round 2
// baseline (1519.015 us; speedup 1.0000x reference)
//
#include <hip/hip_runtime.h>
#include <hip/hip_bf16.h>
#include <math.h>

#define TSTEPS 60
#define DIN 6
#define G3 192

// readlane broadcast: value of lane j (uniform j) -> all lanes (SGPR)
__device__ __forceinline__ float rl(float v, int j) {
    return __int_as_float(__builtin_amdgcn_readlane(__float_as_int(v), j));
}
__device__ __forceinline__ float sigf(float x) { return 1.0f / (1.0f + expf(-x)); }

// ---------------------------------------------------------------------------
// K1: fused 2-layer GRU over all 60 timesteps.
// 256 blocks x 256 threads; 32 rows/block; thread (cr = tid&63, rr = tid>>6)
// owns gate-unit cr for rows rr*8..rr*8+7. h-state lives in REGISTERS,
// broadcast across the wave via v_readlane (wave-lockstep => no syncthreads
// in the time loop; each wave is self-contained for its 8 rows).
// LDS: 3 transposed 192x64 weight matrices, fp32 = 147456 B.
// Precise activations (ocml expf/tanhf, IEEE div) — recurrence amplifies
// per-step rounding ~1e3x over 120 steps.
// ---------------------------------------------------------------------------
__global__ __launch_bounds__(256)
void gru_fused(const float* __restrict__ x,
               const float* __restrict__ Wih0, const float* __restrict__ Whh0,
               const float* __restrict__ bih0, const float* __restrict__ bhh0,
               const float* __restrict__ Wih1, const float* __restrict__ Whh1,
               const float* __restrict__ bih1, const float* __restrict__ bhh1,
               float* __restrict__ hidden)
{
    extern __shared__ float lds[];
    float* W0h = lds;              // Whh0^T  [j=64][192]
    float* W1i = lds + 12288;      // Wih1^T  [j=64][192]
    float* W1h = lds + 24576;      // Whh1^T  [j=64][192]

    const int tid = threadIdx.x;
    const int cr  = tid & 63;
    const int rr  = tid >> 6;      // 0..3
    const int r0  = rr * 8;
    const int n0  = blockIdx.x * 32;

    for (int i = tid; i < G3 * 64; i += 256) {
        int o = i >> 6, j = i & 63;          // W[o][j], o in [0,192)
        W0h[j * G3 + o] = Whh0[i];
        W1i[j * G3 + o] = Wih1[i];
        W1h[j * G3 + o] = Whh1[i];
    }

    float Wx[3][DIN];
    float bi0[3], bh0[3], bi1[3], bh1[3];
#pragma unroll
    for (int g = 0; g < 3; ++g) {
#pragma unroll
        for (int d = 0; d < DIN; ++d) Wx[g][d] = Wih0[(g * 64 + cr) * DIN + d];
        bi0[g] = bih0[g * 64 + cr]; bh0[g] = bhh0[g * 64 + cr];
        bi1[g] = bih1[g * 64 + cr]; bh1[g] = bhh1[g * 64 + cr];
    }
    float h0[8], h1[8];
#pragma unroll
    for (int ri = 0; ri < 8; ++ri) { h0[ri] = 0.f; h1[ri] = 0.f; }

    __syncthreads();

    for (int t = 0; t < TSTEPS; ++t) {
        // ---- layer 0: x-part (row addr is wave-uniform -> broadcast loads)
        float g0[8], g1[8], g2[8];
#pragma unroll
        for (int ri = 0; ri < 8; ++ri) {
            const float* xr = x + (size_t)(n0 + r0 + ri) * (DIN * TSTEPS) + t;
            float s0 = 0.f, s1 = 0.f, s2 = 0.f;
#pragma unroll
            for (int d = 0; d < DIN; ++d) {
                float xv = xr[d * TSTEPS];
                s0 += Wx[0][d] * xv; s1 += Wx[1][d] * xv; s2 += Wx[2][d] * xv;
            }
            g0[ri] = s0; g1[ri] = s1; g2[ri] = s2;
        }

        // ---- layer 0: h-dot (weights from LDS, h via readlane broadcast)
        float a0[8], a1[8], a2[8];
#pragma unroll
        for (int ri = 0; ri < 8; ++ri) { a0[ri] = 0.f; a1[ri] = 0.f; a2[ri] = 0.f; }
#pragma unroll 4
        for (int j = 0; j < 64; ++j) {
            float w0 = W0h[j * G3 + cr];
            float w1 = W0h[j * G3 + cr + 64];
            float w2 = W0h[j * G3 + cr + 128];
#pragma unroll
            for (int ri = 0; ri < 8; ++ri) {
                float hj = rl(h0[ri], j);
                a0[ri] += w0 * hj; a1[ri] += w1 * hj; a2[ri] += w2 * hj;
            }
        }
#pragma unroll
        for (int ri = 0; ri < 8; ++ri) {
            float r = sigf(g0[ri] + bi0[0] + a0[ri] + bh0[0]);
            float z = sigf(g1[ri] + bi0[1] + a1[ri] + bh0[1]);
            float n = tanhf(g2[ri] + bi0[2] + r * (a2[ri] + bh0[2]));
            h0[ri] = (1.f - z) * n + z * h0[ri];
        }

        // ---- layer 1
        float b0[8], b1[8], b2[8], c0[8], c1[8], c2[8];
#pragma unroll
        for (int ri = 0; ri < 8; ++ri) {
            b0[ri] = 0.f; b1[ri] = 0.f; b2[ri] = 0.f;
            c0[ri] = 0.f; c1[ri] = 0.f; c2[ri] = 0.f;
        }
#pragma unroll 2
        for (int j = 0; j < 64; ++j) {
            float wi0 = W1i[j * G3 + cr];
            float wi1 = W1i[j * G3 + cr + 64];
            float wi2 = W1i[j * G3 + cr + 128];
            float wh0 = W1h[j * G3 + cr];
            float wh1 = W1h[j * G3 + cr + 64];
            float wh2 = W1h[j * G3 + cr + 128];
#pragma unroll
            for (int ri = 0; ri < 8; ++ri) {
                float h0j = rl(h0[ri], j);
                float h1j = rl(h1[ri], j);
                b0[ri] += wi0 * h0j; b1[ri] += wi1 * h0j; b2[ri] += wi2 * h0j;
                c0[ri] += wh0 * h1j; c1[ri] += wh1 * h1j; c2[ri] += wh2 * h1j;
            }
        }
#pragma unroll
        for (int ri = 0; ri < 8; ++ri) {
            float r = sigf(b0[ri] + bi1[0] + c0[ri] + bh1[0]);
            float z = sigf(b1[ri] + bi1[1] + c1[ri] + bh1[1]);
            float n = tanhf(b2[ri] + bi1[2] + r * (c2[ri] + bh1[2]));
            h1[ri] = (1.f - z) * n + z * h1[ri];
        }
    }

#pragma unroll
    for (int ri = 0; ri < 8; ++ri)
        hidden[(size_t)(n0 + r0 + ri) * 64 + cr] = h1[ri];
}

// ---------------------------------------------------------------------------
// K2: t = hidden @ transfer_W.T + b ; s1 = t@a1 ; s2 = t@a2   (4 rows/block)
// ---------------------------------------------------------------------------
__global__ __launch_bounds__(256)
void attn_prep(const float* __restrict__ hidden, const float* __restrict__ tW,
               const float* __restrict__ tb, const float* __restrict__ a,
               float* __restrict__ s1, float* __restrict__ s2)
{
    __shared__ float WT[64 * 64];
    __shared__ float hrow[4][64];
    int tid = threadIdx.x, c = tid & 63, rw = tid >> 6;
    for (int i = tid; i < 4096; i += 256) { int cc = i >> 6, u = i & 63; WT[u * 64 + cc] = tW[i]; }
    int row = blockIdx.x * 4 + rw;
    hrow[rw][c] = hidden[(size_t)row * 64 + c];
    __syncthreads();
    float tc = tb[c];
    for (int u = 0; u < 64; ++u) tc += WT[u * 64 + c] * hrow[rw][u];
    float p1 = tc * a[c], p2 = tc * a[64 + c];
#pragma unroll
    for (int o = 32; o; o >>= 1) { p1 += __shfl_xor(p1, o); p2 += __shfl_xor(p2, o); }
    if (c == 0) { s1[row] = p1; s2[row] = p2; }
}

// ---------------------------------------------------------------------------
// K3: bitonic sort of s1 (ascending) with permutation, single block.
// NOTE: needs 65536 B dynamic LDS — round-1 bug was launching this with 0.
// ---------------------------------------------------------------------------
__global__ __launch_bounds__(1024)
void sort_s1(const float* __restrict__ s1, float* __restrict__ s1s, int* __restrict__ perm)
{
    extern __shared__ float smem[];
    float* key = smem;                 // [8192]
    int*   idx = (int*)(smem + 8192);  // [8192]
    int tid = threadIdx.x;
    for (int i = tid; i < 8192; i += 1024) { key[i] = s1[i]; idx[i] = i; }
    __syncthreads();
    for (int sz = 2; sz <= 8192; sz <<= 1) {
        for (int stride = sz >> 1; stride > 0; stride >>= 1) {
            for (int p = tid; p < 4096; p += 1024) {
                int low = p & (stride - 1);
                int i = ((p - low) << 1) + low;
                int j = i + stride;
                bool asc = (i & sz) == 0;
                float ki = key[i], kj = key[j];
                bool sw = asc ? (ki > kj) : (ki < kj);
                if (sw) {
                    key[i] = kj; key[j] = ki;
                    int tmp = idx[i]; idx[i] = idx[j]; idx[j] = tmp;
                }
            }
            __syncthreads();
        }
    }
    for (int i = tid; i < 8192; i += 1024) { s1s[i] = key[i]; perm[i] = idx[i]; }
}

// ---------------------------------------------------------------------------
// K4: branch scans over sorted order. block b: c = b%65 (64 h-channels + scalar),
// b<65: suffix of e^{s1}·h ; b>=65: exclusive prefix of e^{0.01 s1}·h.
// ---------------------------------------------------------------------------
__global__ __launch_bounds__(64)
void scans(const float* __restrict__ s1s, const int* __restrict__ perm,
           const float* __restrict__ hidden,
           float* __restrict__ SufE, float* __restrict__ SufEH,
           float* __restrict__ PreE, float* __restrict__ PreEH)
{
    int lane = threadIdx.x;
    int b = blockIdx.x;
    int c = b % 65;
    bool neg = b >= 65;
    if (!neg) {
        if (lane == 0) { if (c < 64) SufEH[8192 * 64 + c] = 0.f; else SufE[8192] = 0.f; }
        float carry = 0.f;
        for (int ch = 127; ch >= 0; --ch) {
            int k = ch * 64 + lane;
            float e = expf(s1s[k]);
            float v = (c < 64) ? e * hidden[(size_t)perm[k] * 64 + c] : e;
#pragma unroll
            for (int o = 1; o < 64; o <<= 1) {
                float tv = __shfl_down(v, o);
                if (lane + o < 64) v += tv;
            }
            v += carry;
            if (c < 64) SufEH[(size_t)k * 64 + c] = v; else SufE[k] = v;
            carry = __shfl(v, 0);
        }
    } else {
        float carry = 0.f;
        for (int ch = 0; ch < 128; ++ch) {
            int k = ch * 64 + lane;
            float e = expf(0.01f * s1s[k]);
            float term = (c < 64) ? e * hidden[(size_t)perm[k] * 64 + c] : e;
            float v = term;
#pragma unroll
            for (int o = 1; o < 64; o <<= 1) {
                float tv = __shfl_up(v, o);
                if (lane >= o) v += tv;
            }
            float excl = v - term + carry;
            if (c < 64) PreEH[(size_t)k * 64 + c] = excl; else PreE[k] = excl;
            carry += __shfl(v, 63);
        }
        if (lane == 0) { if (c < 64) PreEH[8192 * 64 + c] = carry; else PreE[8192] = carry; }
    }
}

// ---------------------------------------------------------------------------
// K5: per row: binary-search split, combine branch sums -> h_att, +hidden,
// fc + leaky, out dot. 4 rows/block.
// ---------------------------------------------------------------------------
__global__ __launch_bounds__(256)
void finalize(const float* __restrict__ hidden, const float* __restrict__ s1s,
              const float* __restrict__ s2v,
              const float* __restrict__ SufE, const float* __restrict__ SufEH,
              const float* __restrict__ PreE, const float* __restrict__ PreEH,
              const float* __restrict__ fcW, const float* __restrict__ fcb,
              const float* __restrict__ outW, const float* __restrict__ outb,
              float* __restrict__ out)
{
    __shared__ float fcWT[64 * 64];
    __shared__ float h2[4][64];
    int tid = threadIdx.x, c = tid & 63, rw = tid >> 6;
    for (int i = tid; i < 4096; i += 256) { int cc = i >> 6, u = i & 63; fcWT[u * 64 + cc] = fcW[i]; }
    int row = blockIdx.x * 4 + rw;
    float s2 = s2v[row];
    float th = -s2;
    int lo = 0, hi = 8192;
    while (lo < hi) { int mid = (lo + hi) >> 1; if (s1s[mid] > th) hi = mid; else lo = mid + 1; }
    int k = lo;
    float ep = expf(s2);
    float en = expf(0.01f * s2);
    float den = ep * SufE[k] + en * PreE[k];
    float num = ep * SufEH[(size_t)k * 64 + c] + en * PreEH[(size_t)k * 64 + c];
    h2[rw][c] = num / den + hidden[(size_t)row * 64 + c];
    __syncthreads();
    float y = fcb[c];
    for (int u = 0; u < 64; ++u) y += fcWT[u * 64 + c] * h2[rw][u];
    y = y > 0.f ? y : 0.01f * y;
    float o = y * outW[c];
#pragma unroll
    for (int s = 32; s; s >>= 1) o += __shfl_xor(o, s);
    if (c == 0) out[row] = o + outb[0];
}

extern "C" void kernel_launch(void* const* d_in, const int* in_sizes, int n_in,
                              void* d_out, int out_size, void* d_ws, size_t ws_size,
                              hipStream_t stream)
{
    const float* x     = (const float*)d_in[0];
    const float* Wih0  = (const float*)d_in[1];
    const float* Whh0  = (const float*)d_in[2];
    const float* bih0  = (const float*)d_in[3];
    const float* bhh0  = (const float*)d_in[4];
    const float* Wih1  = (const float*)d_in[5];
    const float* Whh1  = (const float*)d_in[6];
    const float* bih1  = (const float*)d_in[7];
    const float* bhh1  = (const float*)d_in[8];
    const float* tW    = (const float*)d_in[9];
    const float* tb    = (const float*)d_in[10];
    const float* a     = (const float*)d_in[11];
    const float* fcW   = (const float*)d_in[12];
    const float* fcb   = (const float*)d_in[13];
    const float* outW  = (const float*)d_in[14];
    const float* outb  = (const float*)d_in[15];

    float* ws     = (float*)d_ws;
    float* hidden = ws;                       // 8192*64
    float* s1     = hidden + 8192 * 64;       // 8192
    float* s2     = s1 + 8192;                // 8192
    float* s1s    = s2 + 8192;                // 8192
    int*   perm   = (int*)(s1s + 8192);       // 8192
    float* SufE   = (float*)(perm + 8192);    // 8200 (8193 used)
    float* PreE   = SufE + 8200;              // 8200
    float* SufEH  = PreE + 8200;              // 8193*64
    float* PreEH  = SufEH + 8193 * 64;        // 8193*64

    // set dynamic-LDS caps once (skip while graph-capturing; attrs persist)
    hipStreamCaptureStatus cap = hipStreamCaptureStatusNone;
    hipStreamIsCapturing(stream, &cap);
    if (cap == hipStreamCaptureStatusNone) {
        hipFuncSetAttribute(reinterpret_cast<const void*>(gru_fused),
                            hipFuncAttributeMaxDynamicSharedMemorySize, 147456);
        hipFuncSetAttribute(reinterpret_cast<const void*>(sort_s1),
                            hipFuncAttributeMaxDynamicSharedMemorySize, 65536);
    }

    gru_fused<<<256, 256, 147456, stream>>>(x, Wih0, Whh0, bih0, bhh0,
                                            Wih1, Whh1, bih1, bhh1, hidden);
    attn_prep<<<2048, 256, 0, stream>>>(hidden, tW, tb, a, s1, s2);
    sort_s1<<<1, 1024, 65536, stream>>>(s1, s1s, perm);
    scans<<<130, 64, 0, stream>>>(s1s, perm, hidden, SufE, SufEH, PreE, PreEH);
    finalize<<<2048, 256, 0, stream>>>(hidden, s1s, s2, SufE, SufEH, PreE, PreEH,
                                       fcW, fcb, outW, outb, (float*)d_out);
}

// Round 3
// 1100.422 us; speedup vs baseline: 1.3804x; 1.3804x over previous
//
#include <hip/hip_runtime.h>
#include <hip/hip_bf16.h>
#include <math.h>

#define TSTEPS 60
#define DIN 6

__device__ __forceinline__ float fast_rcp(float x) { return __builtin_amdgcn_rcpf(x); }
__device__ __forceinline__ float sigf(float x) { return fast_rcp(1.0f + __expf(-x)); }
__device__ __forceinline__ float tanhf_(float x) {
    return 1.0f - 2.0f * fast_rcp(__expf(2.0f * x) + 1.0f);
}

// ---------------------------------------------------------------------------
// K1: fused 2-layer GRU, 60 steps. 256 blocks x 512 threads (8 waves = 2/SIMD).
// 32 rows/block. lane = 32*half + row; (wave w, half hf) owns units u0..u0+3,
// u0 = 8w+4hf. Full h-row in registers (float4 h0q[16]); weights read from LDS
// as 2-address b128 broadcasts (free); h exchanged through XOR-swizzled LDS
// (granule q stored at q^(row&15)); 2 barriers/step. Fast activations.
// LDS: 3*192*64*4 (identity-copy weights) + 2*32*64*4 (h) = 163840 B = 160 KB.
// ---------------------------------------------------------------------------
__global__ __launch_bounds__(512, 2)
void gru_fused(const float* __restrict__ x,
               const float* __restrict__ Wih0, const float* __restrict__ Whh0,
               const float* __restrict__ bih0, const float* __restrict__ bhh0,
               const float* __restrict__ Wih1, const float* __restrict__ Whh1,
               const float* __restrict__ bih1, const float* __restrict__ bhh1,
               float* __restrict__ hidden)
{
    extern __shared__ float lds[];
    float* W0  = lds;            // [192][64]
    float* W1i = lds + 12288;    // [192][64]
    float* W1h = lds + 24576;    // [192][64]
    float* h0x = lds + 36864;    // [32][64] swizzled
    float* h1x = lds + 38912;    // [32][64] swizzled

    const int tid  = threadIdx.x;
    const int lane = tid & 63;
    const int w    = tid >> 6;       // wave 0..7
    const int row  = lane & 31;
    const int hf   = lane >> 5;
    const int u0   = w * 8 + hf * 4; // my 4 units
    const int n0   = blockIdx.x * 32;

    // staging: linear (conflict-free, coalesced) — weight layout is identity
    for (int i = tid; i < 12288; i += 512) {
        W0[i] = Whh0[i]; W1i[i] = Wih1[i]; W1h[i] = Whh1[i];
    }
    for (int i = tid; i < 4096; i += 512) h0x[i] = 0.f;  // covers h0x+h1x

    // per-lane x-weights and biases
    float Wxr[4][DIN], Wxz[4][DIN], Wxn[4][DIN];
    float fr0[4], fz0[4], bnx0[4], bnh0[4];
    float fr1[4], fz1[4], bnx1[4], bnh1[4];
#pragma unroll
    for (int i = 0; i < 4; ++i) {
        int u = u0 + i;
#pragma unroll
        for (int d = 0; d < DIN; ++d) {
            Wxr[i][d] = Wih0[(u)       * DIN + d];
            Wxz[i][d] = Wih0[(64 + u)  * DIN + d];
            Wxn[i][d] = Wih0[(128 + u) * DIN + d];
        }
        fr0[i]  = bih0[u]       + bhh0[u];
        fz0[i]  = bih0[64 + u]  + bhh0[64 + u];
        bnx0[i] = bih0[128 + u];
        bnh0[i] = bhh0[128 + u];
        fr1[i]  = bih1[u]       + bhh1[u];
        fz1[i]  = bih1[64 + u]  + bhh1[64 + u];
        bnx1[i] = bih1[128 + u];
        bnh1[i] = bhh1[128 + u];
    }

    float4 h0q[16];
#pragma unroll
    for (int q = 0; q < 16; ++q) h0q[q] = make_float4(0.f, 0.f, 0.f, 0.f);
    float myh0[4] = {0.f, 0.f, 0.f, 0.f};
    float myh1[4] = {0.f, 0.f, 0.f, 0.f};

    const int swz = row & 15;
    const int hb  = row * 256 + (swz << 4);       // byte base in h0x/h1x
    const int qmy = u0 >> 2;                      // my granule
    const float* W0u  = W0  + u0 * 64;
    const float* W1iu = W1i + u0 * 64;
    const float* W1hu = W1h + u0 * 64;
    const float* xrow = x + (size_t)(n0 + row) * (DIN * TSTEPS);

    __syncthreads();

    float xv[DIN];
#pragma unroll
    for (int d = 0; d < DIN; ++d) xv[d] = xrow[d * TSTEPS];

#pragma unroll 1
    for (int t = 0; t < TSTEPS; ++t) {
        // prefetch next step's x
        float xn[DIN];
        int tn = (t < TSTEPS - 1) ? t + 1 : t;
#pragma unroll
        for (int d = 0; d < DIN; ++d) xn[d] = xrow[d * TSTEPS + tn];

        // ===== layer 0 =====
        float ar[4], az[4], anx[4], anh[4];
#pragma unroll
        for (int i = 0; i < 4; ++i) {
            ar[i] = fr0[i]; az[i] = fz0[i]; anx[i] = bnx0[i]; anh[i] = bnh0[i];
        }
#pragma unroll
        for (int d = 0; d < DIN; ++d) {
            float xd = xv[d];
#pragma unroll
            for (int i = 0; i < 4; ++i) {
                ar[i]  = fmaf(Wxr[i][d], xd, ar[i]);
                az[i]  = fmaf(Wxz[i][d], xd, az[i]);
                anx[i] = fmaf(Wxn[i][d], xd, anx[i]);
            }
        }
#pragma unroll
        for (int q = 0; q < 16; ++q) {
            float4 h = h0q[q];
#pragma unroll
            for (int i = 0; i < 4; ++i) {
                float4 wr = *(const float4*)(W0u + i * 64 + 4 * q);
                float4 wz = *(const float4*)(W0u + 4096 + i * 64 + 4 * q);
                float4 wn = *(const float4*)(W0u + 8192 + i * 64 + 4 * q);
                ar[i]  = fmaf(wr.x, h.x, fmaf(wr.y, h.y, fmaf(wr.z, h.z, fmaf(wr.w, h.w, ar[i]))));
                az[i]  = fmaf(wz.x, h.x, fmaf(wz.y, h.y, fmaf(wz.z, h.z, fmaf(wz.w, h.w, az[i]))));
                anh[i] = fmaf(wn.x, h.x, fmaf(wn.y, h.y, fmaf(wn.z, h.z, fmaf(wn.w, h.w, anh[i]))));
            }
        }
        float h0n[4];
#pragma unroll
        for (int i = 0; i < 4; ++i) {
            float r = sigf(ar[i]);
            float z = sigf(az[i]);
            float n = tanhf_(anx[i] + r * anh[i]);
            h0n[i] = (1.f - z) * n + z * myh0[i];
            myh0[i] = h0n[i];
        }
        *(float4*)((char*)h0x + (hb ^ (qmy << 4))) =
            make_float4(h0n[0], h0n[1], h0n[2], h0n[3]);
        __syncthreads();   // B1: new h0 visible
#pragma unroll
        for (int q = 0; q < 16; ++q)
            h0q[q] = *(const float4*)((const char*)h0x + (hb ^ (q << 4)));

        // ===== layer 1 =====
        float br[4], bz[4], cnx[4], cnh[4];
#pragma unroll
        for (int i = 0; i < 4; ++i) {
            br[i] = fr1[i]; bz[i] = fz1[i]; cnx[i] = bnx1[i]; cnh[i] = bnh1[i];
        }
#pragma unroll
        for (int q = 0; q < 16; ++q) {
            float4 h0v = h0q[q];
            float4 h1v = *(const float4*)((const char*)h1x + (hb ^ (q << 4)));
#pragma unroll
            for (int i = 0; i < 4; ++i) {
                float4 a1 = *(const float4*)(W1iu + i * 64 + 4 * q);
                float4 a2 = *(const float4*)(W1iu + 4096 + i * 64 + 4 * q);
                float4 a3 = *(const float4*)(W1iu + 8192 + i * 64 + 4 * q);
                float4 b1 = *(const float4*)(W1hu + i * 64 + 4 * q);
                float4 b2 = *(const float4*)(W1hu + 4096 + i * 64 + 4 * q);
                float4 b3 = *(const float4*)(W1hu + 8192 + i * 64 + 4 * q);
                br[i]  = fmaf(a1.x, h0v.x, fmaf(a1.y, h0v.y, fmaf(a1.z, h0v.z, fmaf(a1.w, h0v.w, br[i]))));
                br[i]  = fmaf(b1.x, h1v.x, fmaf(b1.y, h1v.y, fmaf(b1.z, h1v.z, fmaf(b1.w, h1v.w, br[i]))));
                bz[i]  = fmaf(a2.x, h0v.x, fmaf(a2.y, h0v.y, fmaf(a2.z, h0v.z, fmaf(a2.w, h0v.w, bz[i]))));
                bz[i]  = fmaf(b2.x, h1v.x, fmaf(b2.y, h1v.y, fmaf(b2.z, h1v.z, fmaf(b2.w, h1v.w, bz[i]))));
                cnx[i] = fmaf(a3.x, h0v.x, fmaf(a3.y, h0v.y, fmaf(a3.z, h0v.z, fmaf(a3.w, h0v.w, cnx[i]))));
                cnh[i] = fmaf(b3.x, h1v.x, fmaf(b3.y, h1v.y, fmaf(b3.z, h1v.z, fmaf(b3.w, h1v.w, cnh[i]))));
            }
        }
        __syncthreads();   // B2: all h1x reads done
        float h1n[4];
#pragma unroll
        for (int i = 0; i < 4; ++i) {
            float r = sigf(br[i]);
            float z = sigf(bz[i]);
            float n = tanhf_(cnx[i] + r * cnh[i]);
            h1n[i] = (1.f - z) * n + z * myh1[i];
            myh1[i] = h1n[i];
        }
        *(float4*)((char*)h1x + (hb ^ (qmy << 4))) =
            make_float4(h1n[0], h1n[1], h1n[2], h1n[3]);
#pragma unroll
        for (int d = 0; d < DIN; ++d) xv[d] = xn[d];
    }

    __syncthreads();
    // epilogue: linear write of h1 (unswizzle), coalesced float4
    {
        int r2 = tid >> 4, q2 = tid & 15;
        float4 v = *(const float4*)((const char*)h1x +
                       ((r2 * 256 + ((r2 & 15) << 4)) ^ (q2 << 4)));
        *(float4*)(hidden + (size_t)(n0 + r2) * 64 + q2 * 4) = v;
    }
}

// ---------------------------------------------------------------------------
// K2: t = hidden @ transfer_W.T + b ; s1 = t@a1 ; s2 = t@a2   (4 rows/block)
// ---------------------------------------------------------------------------
__global__ __launch_bounds__(256)
void attn_prep(const float* __restrict__ hidden, const float* __restrict__ tW,
               const float* __restrict__ tb, const float* __restrict__ a,
               float* __restrict__ s1, float* __restrict__ s2)
{
    __shared__ float WT[64 * 64];
    __shared__ float hrow[4][64];
    int tid = threadIdx.x, c = tid & 63, rw = tid >> 6;
    // WT[u*64+c] = tW[c*64+u]; linear LDS writes (no bank conflict)
    for (int i = tid; i < 4096; i += 256) WT[i] = tW[(i & 63) * 64 + (i >> 6)];
    int row = blockIdx.x * 4 + rw;
    hrow[rw][c] = hidden[(size_t)row * 64 + c];
    __syncthreads();
    float tc = tb[c];
    for (int u = 0; u < 64; ++u) tc += WT[u * 64 + c] * hrow[rw][u];
    float p1 = tc * a[c], p2 = tc * a[64 + c];
#pragma unroll
    for (int o = 32; o; o >>= 1) { p1 += __shfl_xor(p1, o); p2 += __shfl_xor(p2, o); }
    if (c == 0) { s1[row] = p1; s2[row] = p2; }
}

// ---------------------------------------------------------------------------
// K3: bitonic sort of s1 (ascending) with permutation, single block.
// ---------------------------------------------------------------------------
__global__ __launch_bounds__(1024)
void sort_s1(const float* __restrict__ s1, float* __restrict__ s1s, int* __restrict__ perm)
{
    extern __shared__ float smem[];
    float* key = smem;                 // [8192]
    int*   idx = (int*)(smem + 8192);  // [8192]
    int tid = threadIdx.x;
    for (int i = tid; i < 8192; i += 1024) { key[i] = s1[i]; idx[i] = i; }
    __syncthreads();
    for (int sz = 2; sz <= 8192; sz <<= 1) {
        for (int stride = sz >> 1; stride > 0; stride >>= 1) {
            for (int p = tid; p < 4096; p += 1024) {
                int low = p & (stride - 1);
                int i = ((p - low) << 1) + low;
                int j = i + stride;
                bool asc = (i & sz) == 0;
                float ki = key[i], kj = key[j];
                bool sw = asc ? (ki > kj) : (ki < kj);
                if (sw) {
                    key[i] = kj; key[j] = ki;
                    int tmp = idx[i]; idx[i] = idx[j]; idx[j] = tmp;
                }
            }
            __syncthreads();
        }
    }
    for (int i = tid; i < 8192; i += 1024) { s1s[i] = key[i]; perm[i] = idx[i]; }
}

// ---------------------------------------------------------------------------
// K4: branch scans over sorted order. block b: c = b%65 (64 h-channels + scalar),
// b<65: suffix of e^{s1}·h ; b>=65: exclusive prefix of e^{0.01 s1}·h.
// ---------------------------------------------------------------------------
__global__ __launch_bounds__(64)
void scans(const float* __restrict__ s1s, const int* __restrict__ perm,
           const float* __restrict__ hidden,
           float* __restrict__ SufE, float* __restrict__ SufEH,
           float* __restrict__ PreE, float* __restrict__ PreEH)
{
    int lane = threadIdx.x;
    int b = blockIdx.x;
    int c = b % 65;
    bool neg = b >= 65;
    if (!neg) {
        if (lane == 0) { if (c < 64) SufEH[8192 * 64 + c] = 0.f; else SufE[8192] = 0.f; }
        float carry = 0.f;
        for (int ch = 127; ch >= 0; --ch) {
            int k = ch * 64 + lane;
            float e = expf(s1s[k]);
            float v = (c < 64) ? e * hidden[(size_t)perm[k] * 64 + c] : e;
#pragma unroll
            for (int o = 1; o < 64; o <<= 1) {
                float tv = __shfl_down(v, o);
                if (lane + o < 64) v += tv;
            }
            v += carry;
            if (c < 64) SufEH[(size_t)k * 64 + c] = v; else SufE[k] = v;
            carry = __shfl(v, 0);
        }
    } else {
        float carry = 0.f;
        for (int ch = 0; ch < 128; ++ch) {
            int k = ch * 64 + lane;
            float e = expf(0.01f * s1s[k]);
            float term = (c < 64) ? e * hidden[(size_t)perm[k] * 64 + c] : e;
            float v = term;
#pragma unroll
            for (int o = 1; o < 64; o <<= 1) {
                float tv = __shfl_up(v, o);
                if (lane >= o) v += tv;
            }
            float excl = v - term + carry;
            if (c < 64) PreEH[(size_t)k * 64 + c] = excl; else PreE[k] = excl;
            carry += __shfl(v, 63);
        }
        if (lane == 0) { if (c < 64) PreEH[8192 * 64 + c] = carry; else PreE[8192] = carry; }
    }
}

// ---------------------------------------------------------------------------
// K5: per row: binary-search split, combine branch sums -> h_att, +hidden,
// fc + leaky, out dot. 4 rows/block.
// ---------------------------------------------------------------------------
__global__ __launch_bounds__(256)
void finalize(const float* __restrict__ hidden, const float* __restrict__ s1s,
              const float* __restrict__ s2v,
              const float* __restrict__ SufE, const float* __restrict__ SufEH,
              const float* __restrict__ PreE, const float* __restrict__ PreEH,
              const float* __restrict__ fcW, const float* __restrict__ fcb,
              const float* __restrict__ outW, const float* __restrict__ outb,
              float* __restrict__ out)
{
    __shared__ float fcWT[64 * 64];
    __shared__ float h2[4][64];
    int tid = threadIdx.x, c = tid & 63, rw = tid >> 6;
    for (int i = tid; i < 4096; i += 256) fcWT[i] = fcW[(i & 63) * 64 + (i >> 6)];
    int row = blockIdx.x * 4 + rw;
    float s2 = s2v[row];
    float th = -s2;
    int lo = 0, hi = 8192;
    while (lo < hi) { int mid = (lo + hi) >> 1; if (s1s[mid] > th) hi = mid; else lo = mid + 1; }
    int k = lo;
    float ep = expf(s2);
    float en = expf(0.01f * s2);
    float den = ep * SufE[k] + en * PreE[k];
    float num = ep * SufEH[(size_t)k * 64 + c] + en * PreEH[(size_t)k * 64 + c];
    h2[rw][c] = num / den + hidden[(size_t)row * 64 + c];
    __syncthreads();
    float y = fcb[c];
    for (int u = 0; u < 64; ++u) y += fcWT[u * 64 + c] * h2[rw][u];
    y = y > 0.f ? y : 0.01f * y;
    float o = y * outW[c];
#pragma unroll
    for (int s = 32; s; s >>= 1) o += __shfl_xor(o, s);
    if (c == 0) out[row] = o + outb[0];
}

extern "C" void kernel_launch(void* const* d_in, const int* in_sizes, int n_in,
                              void* d_out, int out_size, void* d_ws, size_t ws_size,
                              hipStream_t stream)
{
    const float* x     = (const float*)d_in[0];
    const float* Wih0  = (const float*)d_in[1];
    const float* Whh0  = (const float*)d_in[2];
    const float* bih0  = (const float*)d_in[3];
    const float* bhh0  = (const float*)d_in[4];
    const float* Wih1  = (const float*)d_in[5];
    const float* Whh1  = (const float*)d_in[6];
    const float* bih1  = (const float*)d_in[7];
    const float* bhh1  = (const float*)d_in[8];
    const float* tW    = (const float*)d_in[9];
    const float* tb    = (const float*)d_in[10];
    const float* a     = (const float*)d_in[11];
    const float* fcW   = (const float*)d_in[12];
    const float* fcb   = (const float*)d_in[13];
    const float* outW  = (const float*)d_in[14];
    const float* outb  = (const float*)d_in[15];

    float* ws     = (float*)d_ws;
    float* hidden = ws;                       // 8192*64
    float* s1     = hidden + 8192 * 64;       // 8192
    float* s2     = s1 + 8192;                // 8192
    float* s1s    = s2 + 8192;                // 8192
    int*   perm   = (int*)(s1s + 8192);       // 8192
    float* SufE   = (float*)(perm + 8192);    // 8200 (8193 used)
    float* PreE   = SufE + 8200;              // 8200
    float* SufEH  = PreE + 8200;              // 8193*64
    float* PreEH  = SufEH + 8193 * 64;        // 8193*64

    // set dynamic-LDS caps once (skip while graph-capturing; attrs persist)
    hipStreamCaptureStatus cap = hipStreamCaptureStatusNone;
    hipStreamIsCapturing(stream, &cap);
    if (cap == hipStreamCaptureStatusNone) {
        hipFuncSetAttribute(reinterpret_cast<const void*>(gru_fused),
                            hipFuncAttributeMaxDynamicSharedMemorySize, 163840);
        hipFuncSetAttribute(reinterpret_cast<const void*>(sort_s1),
                            hipFuncAttributeMaxDynamicSharedMemorySize, 65536);
    }

    gru_fused<<<256, 512, 163840, stream>>>(x, Wih0, Whh0, bih0, bhh0,
                                            Wih1, Whh1, bih1, bhh1, hidden);
    attn_prep<<<2048, 256, 0, stream>>>(hidden, tW, tb, a, s1, s2);
    sort_s1<<<1, 1024, 65536, stream>>>(s1, s1s, perm);
    scans<<<130, 64, 0, stream>>>(s1s, perm, hidden, SufE, SufEH, PreE, PreEH);
    finalize<<<2048, 256, 0, stream>>>(hidden, s1s, s2, SufE, SufEH, PreE, PreEH,
                                       fcW, fcb, outW, outb, (float*)d_out);
}

// Round 4
// 483.312 us; speedup vs baseline: 3.1429x; 2.2768x over previous
//
#include <hip/hip_runtime.h>
#include <hip/hip_bf16.h>
#include <math.h>

#define TSTEPS 60
#define DIN 6

typedef __attribute__((ext_vector_type(8))) short short8v;
typedef __attribute__((ext_vector_type(4))) float f32x4;
#define MFMA16 __builtin_amdgcn_mfma_f32_16x16x32_bf16

__device__ __forceinline__ float fast_rcp(float x) { return __builtin_amdgcn_rcpf(x); }
__device__ __forceinline__ float sigf(float x) { return fast_rcp(1.0f + __expf(-x)); }
__device__ __forceinline__ float tanhf_(float x) {
    return 1.0f - 2.0f * fast_rcp(__expf(2.0f * x) + 1.0f);
}
__device__ __forceinline__ unsigned short f2bf(float f) {   // RTN-even
    unsigned u = __float_as_uint(f);
    u += 0x7fff + ((u >> 16) & 1);
    return (unsigned short)(u >> 16);
}
__device__ __forceinline__ float bf2f(unsigned short s) {
    return __uint_as_float(((unsigned)s) << 16);
}

// ---------------------------------------------------------------------------
// K1: fused 2-layer GRU, 60 steps, MFMA split-bf16 (hi+lo, 3-term) matmuls.
// 256 blocks x 512 threads (8 waves). 32 rows/block. Wave (mt=w>>2, ur=w&3)
// owns C-tile rows 16mt..+15 x units 16ur..+15 for all 3 gates (lane-local
// activations; c/d: col=lane&15, row=(lane>>4)*4+reg [m89-verified]).
// Weights: LDS bf16 hi/lo planes [192][64], XOR-swizzled 16B granules
// (g' = g ^ (u&7)) -> full-width b128 frag reads; layer-0 B-frags persist in
// registers (12 frags, 96 VGPR). h state: fp32 in owner registers (never
// quantized); bf16 hi/lo copies in LDS planes for next matmul's A-frags.
// LDS: 6 weight planes 147456 + 4 h planes 16384 = 163840 B.
// ---------------------------------------------------------------------------
__global__ __launch_bounds__(512, 1)
void gru_fused(const float* __restrict__ x,
               const float* __restrict__ Wih0, const float* __restrict__ Whh0,
               const float* __restrict__ bih0, const float* __restrict__ bhh0,
               const float* __restrict__ Wih1, const float* __restrict__ Whh1,
               const float* __restrict__ bih1, const float* __restrict__ bhh1,
               float* __restrict__ hidden)
{
    extern __shared__ char ldsb[];
    // plane byte bases
    const int W0H = 0, W0L = 24576, W1IH = 49152, W1IL = 73728,
              W1HH = 98304, W1HL = 122880, HP = 147456;
    // h planes: h0_hi @HP, h0_lo @HP+4096, h1_hi @HP+8192, h1_lo @HP+12288

    const int tid = threadIdx.x;
    const int l   = tid & 63;
    const int w   = tid >> 6;
    const int mt  = w >> 2;          // m-tile 0..1
    const int ur  = w & 3;           // unit-range 0..3
    const int l15 = l & 15;
    const int kb  = l >> 4;          // k-block 0..3
    const int u_m = ur * 16 + l15;   // my unit column (0..63)
    const int n0  = blockIdx.x * 32;

    // ---- stage weights as swizzled bf16 hi/lo planes (one-time) ----
    for (int i = tid; i < 12288; i += 512) {
        int u = i >> 6, j = i & 63;
        int off = u * 128 + (((j >> 3) ^ (u & 7)) << 4) + (j & 7) * 2;
        float w0 = Whh0[i], w1 = Wih1[i], w2 = Whh1[i];
        unsigned short h0 = f2bf(w0); unsigned short l0 = f2bf(w0 - bf2f(h0));
        unsigned short h1 = f2bf(w1); unsigned short l1 = f2bf(w1 - bf2f(h1));
        unsigned short h2 = f2bf(w2); unsigned short l2 = f2bf(w2 - bf2f(h2));
        *(unsigned short*)(ldsb + W0H  + off) = h0;
        *(unsigned short*)(ldsb + W0L  + off) = l0;
        *(unsigned short*)(ldsb + W1IH + off) = h1;
        *(unsigned short*)(ldsb + W1IL + off) = l1;
        *(unsigned short*)(ldsb + W1HH + off) = h2;
        *(unsigned short*)(ldsb + W1HL + off) = l2;
    }
    for (int i = tid; i < 4096; i += 512) *(unsigned*)(ldsb + HP + i * 4) = 0u;

    // ---- per-lane constants ----
    float brz0_r = bih0[u_m] + bhh0[u_m];
    float brz0_z = bih0[64 + u_m] + bhh0[64 + u_m];
    float bi0n = bih0[128 + u_m], bh0n = bhh0[128 + u_m];
    float brz1_r = bih1[u_m] + bhh1[u_m];
    float brz1_z = bih1[64 + u_m] + bhh1[64 + u_m];
    float bi1n = bih1[128 + u_m], bh1n = bhh1[128 + u_m];

    float Wx[3][DIN];
#pragma unroll
    for (int g = 0; g < 3; ++g)
#pragma unroll
        for (int d = 0; d < DIN; ++d) Wx[g][d] = Wih0[(g * 64 + u_m) * DIN + d];

    // fragment addresses
    const int rowA = mt * 16 + l15;
    const int bA0 = HP + rowA * 128 + ((kb ^ (rowA & 7)) << 4);
    const int bA1 = bA0 ^ 64;
    const int bB0 = u_m * 128 + ((kb ^ (u_m & 7)) << 4);
    const int bB1 = bB0 ^ 64;
    int wAo[4];
#pragma unroll
    for (int i = 0; i < 4; ++i) {
        int r = mt * 16 + kb * 4 + i;
        wAo[i] = HP + r * 128 + ((((u_m >> 3) & 7) ^ (r & 7)) << 4) + (u_m & 7) * 2;
    }
    const float* xp[4];
#pragma unroll
    for (int i = 0; i < 4; ++i)
        xp[i] = x + (size_t)(n0 + mt * 16 + kb * 4 + i) * (DIN * TSTEPS);

    float h0f[4] = {0.f, 0.f, 0.f, 0.f};
    float h1f[4] = {0.f, 0.f, 0.f, 0.f};

    __syncthreads();

#define LD8(o) (*(const short8v*)(ldsb + (o)))

    // persistent layer-0 B-frags: [gate][plane hi/lo][kt]
    short8v B0[3][2][2];
#pragma unroll
    for (int g = 0; g < 3; ++g) {
        B0[g][0][0] = LD8(W0H + g * 8192 + bB0);
        B0[g][0][1] = LD8(W0H + g * 8192 + bB1);
        B0[g][1][0] = LD8(W0L + g * 8192 + bB0);
        B0[g][1][1] = LD8(W0L + g * 8192 + bB1);
    }

#pragma unroll 1
    for (int t = 0; t < TSTEPS; ++t) {
        // x loads (L1-resident broadcasts)
        float xv[4][DIN];
#pragma unroll
        for (int i = 0; i < 4; ++i)
#pragma unroll
            for (int d = 0; d < DIN; ++d) xv[i][d] = xp[i][d * TSTEPS + t];

        // A-frags of h0(old), h1(old):  [kt][hi/lo]
        short8v aH0[2][2], aH1[2][2];
        aH0[0][0] = LD8(bA0);        aH0[1][0] = LD8(bA1);
        aH0[0][1] = LD8(bA0 + 4096); aH0[1][1] = LD8(bA1 + 4096);
        aH1[0][0] = LD8(bA0 + 8192); aH1[1][0] = LD8(bA1 + 8192);
        aH1[0][1] = LD8(bA0 + 12288); aH1[1][1] = LD8(bA1 + 12288);

        // gi = Wih0 @ x_t (VALU, rows are C-owner rows)
        float gi0[4], gi1[4], gi2[4];
#pragma unroll
        for (int i = 0; i < 4; ++i) {
            float s0 = 0.f, s1 = 0.f, s2 = 0.f;
#pragma unroll
            for (int d = 0; d < DIN; ++d) {
                float xd = xv[i][d];
                s0 = fmaf(Wx[0][d], xd, s0);
                s1 = fmaf(Wx[1][d], xd, s1);
                s2 = fmaf(Wx[2][d], xd, s2);
            }
            gi0[i] = s0; gi1[i] = s1; gi2[i] = s2;
        }

        // ===== layer 0: gh = Whh0 @ h0 =====
        f32x4 Cr, Cz, Cnh;
#pragma unroll
        for (int i = 0; i < 4; ++i) {
            Cr[i] = brz0_r + gi0[i]; Cz[i] = brz0_z + gi1[i]; Cnh[i] = bh0n;
        }
        Cr = MFMA16(aH0[0][0], B0[0][0][0], Cr, 0, 0, 0);
        Cr = MFMA16(aH0[1][0], B0[0][0][1], Cr, 0, 0, 0);
        Cr = MFMA16(aH0[0][1], B0[0][0][0], Cr, 0, 0, 0);
        Cr = MFMA16(aH0[1][1], B0[0][0][1], Cr, 0, 0, 0);
        Cr = MFMA16(aH0[0][0], B0[0][1][0], Cr, 0, 0, 0);
        Cr = MFMA16(aH0[1][0], B0[0][1][1], Cr, 0, 0, 0);
        Cz = MFMA16(aH0[0][0], B0[1][0][0], Cz, 0, 0, 0);
        Cz = MFMA16(aH0[1][0], B0[1][0][1], Cz, 0, 0, 0);
        Cz = MFMA16(aH0[0][1], B0[1][0][0], Cz, 0, 0, 0);
        Cz = MFMA16(aH0[1][1], B0[1][0][1], Cz, 0, 0, 0);
        Cz = MFMA16(aH0[0][0], B0[1][1][0], Cz, 0, 0, 0);
        Cz = MFMA16(aH0[1][0], B0[1][1][1], Cz, 0, 0, 0);
        Cnh = MFMA16(aH0[0][0], B0[2][0][0], Cnh, 0, 0, 0);
        Cnh = MFMA16(aH0[1][0], B0[2][0][1], Cnh, 0, 0, 0);
        Cnh = MFMA16(aH0[0][1], B0[2][0][0], Cnh, 0, 0, 0);
        Cnh = MFMA16(aH0[1][1], B0[2][0][1], Cnh, 0, 0, 0);
        Cnh = MFMA16(aH0[0][0], B0[2][1][0], Cnh, 0, 0, 0);
        Cnh = MFMA16(aH0[1][0], B0[2][1][1], Cnh, 0, 0, 0);

        unsigned short hh[4], hl[4];
#pragma unroll
        for (int i = 0; i < 4; ++i) {
            float r = sigf(Cr[i]);
            float z = sigf(Cz[i]);
            float n = tanhf_(gi2[i] + bi0n + r * Cnh[i]);
            h0f[i] = (1.f - z) * n + z * h0f[i];
            hh[i] = f2bf(h0f[i]);
            hl[i] = f2bf(h0f[i] - bf2f(hh[i]));
        }
        __syncthreads();   // B1: all h0/h1 A-reads done
#pragma unroll
        for (int i = 0; i < 4; ++i) {
            *(unsigned short*)(ldsb + wAo[i]) = hh[i];
            *(unsigned short*)(ldsb + wAo[i] + 4096) = hl[i];
        }
        __syncthreads();   // B2: h0' visible

        // ===== layer 1 =====
        short8v aN[2][2];
        aN[0][0] = LD8(bA0);        aN[1][0] = LD8(bA1);
        aN[0][1] = LD8(bA0 + 4096); aN[1][1] = LD8(bA1 + 4096);

        f32x4 Dr, Dz, Dni, Dnh;
#pragma unroll
        for (int i = 0; i < 4; ++i) {
            Dr[i] = brz1_r; Dz[i] = brz1_z; Dni[i] = bi1n; Dnh[i] = bh1n;
        }
        {   // gate r
            short8v bih_ = LD8(W1IH + bB0), bih1_ = LD8(W1IH + bB1);
            short8v bil_ = LD8(W1IL + bB0), bil1_ = LD8(W1IL + bB1);
            Dr = MFMA16(aN[0][0], bih_, Dr, 0, 0, 0);
            Dr = MFMA16(aN[1][0], bih1_, Dr, 0, 0, 0);
            Dr = MFMA16(aN[0][1], bih_, Dr, 0, 0, 0);
            Dr = MFMA16(aN[1][1], bih1_, Dr, 0, 0, 0);
            Dr = MFMA16(aN[0][0], bil_, Dr, 0, 0, 0);
            Dr = MFMA16(aN[1][0], bil1_, Dr, 0, 0, 0);
            short8v bhh_ = LD8(W1HH + bB0), bhh1_ = LD8(W1HH + bB1);
            short8v bhl_ = LD8(W1HL + bB0), bhl1_ = LD8(W1HL + bB1);
            Dr = MFMA16(aH1[0][0], bhh_, Dr, 0, 0, 0);
            Dr = MFMA16(aH1[1][0], bhh1_, Dr, 0, 0, 0);
            Dr = MFMA16(aH1[0][1], bhh_, Dr, 0, 0, 0);
            Dr = MFMA16(aH1[1][1], bhh1_, Dr, 0, 0, 0);
            Dr = MFMA16(aH1[0][0], bhl_, Dr, 0, 0, 0);
            Dr = MFMA16(aH1[1][0], bhl1_, Dr, 0, 0, 0);
        }
        {   // gate z
            short8v bih_ = LD8(W1IH + 8192 + bB0), bih1_ = LD8(W1IH + 8192 + bB1);
            short8v bil_ = LD8(W1IL + 8192 + bB0), bil1_ = LD8(W1IL + 8192 + bB1);
            Dz = MFMA16(aN[0][0], bih_, Dz, 0, 0, 0);
            Dz = MFMA16(aN[1][0], bih1_, Dz, 0, 0, 0);
            Dz = MFMA16(aN[0][1], bih_, Dz, 0, 0, 0);
            Dz = MFMA16(aN[1][1], bih1_, Dz, 0, 0, 0);
            Dz = MFMA16(aN[0][0], bil_, Dz, 0, 0, 0);
            Dz = MFMA16(aN[1][0], bil1_, Dz, 0, 0, 0);
            short8v bhh_ = LD8(W1HH + 8192 + bB0), bhh1_ = LD8(W1HH + 8192 + bB1);
            short8v bhl_ = LD8(W1HL + 8192 + bB0), bhl1_ = LD8(W1HL + 8192 + bB1);
            Dz = MFMA16(aH1[0][0], bhh_, Dz, 0, 0, 0);
            Dz = MFMA16(aH1[1][0], bhh1_, Dz, 0, 0, 0);
            Dz = MFMA16(aH1[0][1], bhh_, Dz, 0, 0, 0);
            Dz = MFMA16(aH1[1][1], bhh1_, Dz, 0, 0, 0);
            Dz = MFMA16(aH1[0][0], bhl_, Dz, 0, 0, 0);
            Dz = MFMA16(aH1[1][0], bhl1_, Dz, 0, 0, 0);
        }
        {   // gate n (input part and hidden part SEPARATE)
            short8v bih_ = LD8(W1IH + 16384 + bB0), bih1_ = LD8(W1IH + 16384 + bB1);
            short8v bil_ = LD8(W1IL + 16384 + bB0), bil1_ = LD8(W1IL + 16384 + bB1);
            Dni = MFMA16(aN[0][0], bih_, Dni, 0, 0, 0);
            Dni = MFMA16(aN[1][0], bih1_, Dni, 0, 0, 0);
            Dni = MFMA16(aN[0][1], bih_, Dni, 0, 0, 0);
            Dni = MFMA16(aN[1][1], bih1_, Dni, 0, 0, 0);
            Dni = MFMA16(aN[0][0], bil_, Dni, 0, 0, 0);
            Dni = MFMA16(aN[1][0], bil1_, Dni, 0, 0, 0);
            short8v bhh_ = LD8(W1HH + 16384 + bB0), bhh1_ = LD8(W1HH + 16384 + bB1);
            short8v bhl_ = LD8(W1HL + 16384 + bB0), bhl1_ = LD8(W1HL + 16384 + bB1);
            Dnh = MFMA16(aH1[0][0], bhh_, Dnh, 0, 0, 0);
            Dnh = MFMA16(aH1[1][0], bhh1_, Dnh, 0, 0, 0);
            Dnh = MFMA16(aH1[0][1], bhh_, Dnh, 0, 0, 0);
            Dnh = MFMA16(aH1[1][1], bhh1_, Dnh, 0, 0, 0);
            Dnh = MFMA16(aH1[0][0], bhl_, Dnh, 0, 0, 0);
            Dnh = MFMA16(aH1[1][0], bhl1_, Dnh, 0, 0, 0);
        }
#pragma unroll
        for (int i = 0; i < 4; ++i) {
            float r = sigf(Dr[i]);
            float z = sigf(Dz[i]);
            float n = tanhf_(Dni[i] + r * Dnh[i]);
            h1f[i] = (1.f - z) * n + z * h1f[i];
            unsigned short hhi = f2bf(h1f[i]);
            *(unsigned short*)(ldsb + wAo[i] + 8192) = hhi;
            *(unsigned short*)(ldsb + wAo[i] + 12288) = f2bf(h1f[i] - bf2f(hhi));
        }
        __syncthreads();   // B3: h1' visible; next step's reads safe
    }

#pragma unroll
    for (int i = 0; i < 4; ++i)
        hidden[(size_t)(n0 + mt * 16 + kb * 4 + i) * 64 + u_m] = h1f[i];
#undef LD8
}

// ---------------------------------------------------------------------------
// K1b: hiddenT[c][row] = hidden[row][c]  (for L1-resident gathers in scans)
// ---------------------------------------------------------------------------
__global__ __launch_bounds__(256)
void transposeH(const float* __restrict__ hidden, float* __restrict__ hiddenT)
{
    __shared__ float tile[64][65];
    int b = blockIdx.x, tid = threadIdx.x;
    for (int i = tid; i < 4096; i += 256) {
        int r = i >> 6, c = i & 63;
        tile[c][r] = hidden[(size_t)(b * 64 + r) * 64 + c];
    }
    __syncthreads();
    for (int i = tid; i < 4096; i += 256) {
        int c = i >> 6, r = i & 63;
        hiddenT[(size_t)c * 8192 + b * 64 + r] = tile[c][r];
    }
}

// ---------------------------------------------------------------------------
// K2: t = hidden @ transfer_W.T + b ; s1 = t@a1 ; s2 = t@a2   (4 rows/block)
// ---------------------------------------------------------------------------
__global__ __launch_bounds__(256)
void attn_prep(const float* __restrict__ hidden, const float* __restrict__ tW,
               const float* __restrict__ tb, const float* __restrict__ a,
               float* __restrict__ s1, float* __restrict__ s2)
{
    __shared__ float WT[64 * 64];
    __shared__ float hrow[4][64];
    int tid = threadIdx.x, c = tid & 63, rw = tid >> 6;
    for (int i = tid; i < 4096; i += 256) WT[i] = tW[(i & 63) * 64 + (i >> 6)];
    int row = blockIdx.x * 4 + rw;
    hrow[rw][c] = hidden[(size_t)row * 64 + c];
    __syncthreads();
    float tc = tb[c];
    for (int u = 0; u < 64; ++u) tc += WT[u * 64 + c] * hrow[rw][u];
    float p1 = tc * a[c], p2 = tc * a[64 + c];
#pragma unroll
    for (int o = 32; o; o >>= 1) { p1 += __shfl_xor(p1, o); p2 += __shfl_xor(p2, o); }
    if (c == 0) { s1[row] = p1; s2[row] = p2; }
}

// ---------------------------------------------------------------------------
// K3: bitonic sort of s1 (ascending) with permutation, single block.
// ---------------------------------------------------------------------------
__global__ __launch_bounds__(1024)
void sort_s1(const float* __restrict__ s1, float* __restrict__ s1s, int* __restrict__ perm)
{
    extern __shared__ float smem[];
    float* key = smem;                 // [8192]
    int*   idx = (int*)(smem + 8192);  // [8192]
    int tid = threadIdx.x;
    for (int i = tid; i < 8192; i += 1024) { key[i] = s1[i]; idx[i] = i; }
    __syncthreads();
    for (int sz = 2; sz <= 8192; sz <<= 1) {
        for (int stride = sz >> 1; stride > 0; stride >>= 1) {
            for (int p = tid; p < 4096; p += 1024) {
                int low = p & (stride - 1);
                int i = ((p - low) << 1) + low;
                int j = i + stride;
                bool asc = (i & sz) == 0;
                float ki = key[i], kj = key[j];
                bool sw = asc ? (ki > kj) : (ki < kj);
                if (sw) {
                    key[i] = kj; key[j] = ki;
                    int tmp = idx[i]; idx[i] = idx[j]; idx[j] = tmp;
                }
            }
            __syncthreads();
        }
    }
    for (int i = tid; i < 8192; i += 1024) { s1s[i] = key[i]; perm[i] = idx[i]; }
}

// ---------------------------------------------------------------------------
// K4: branch scans over sorted order; hidden gathers from L1-resident hiddenT.
// ---------------------------------------------------------------------------
__global__ __launch_bounds__(64)
void scans(const float* __restrict__ s1s, const int* __restrict__ perm,
           const float* __restrict__ hiddenT,
           float* __restrict__ SufE, float* __restrict__ SufEH,
           float* __restrict__ PreE, float* __restrict__ PreEH)
{
    int lane = threadIdx.x;
    int b = blockIdx.x;
    int c = b % 65;
    bool neg = b >= 65;
    const float* hT = hiddenT + (size_t)(c < 64 ? c : 0) * 8192;
    if (!neg) {
        if (lane == 0) { if (c < 64) SufEH[8192 * 64 + c] = 0.f; else SufE[8192] = 0.f; }
        float carry = 0.f;
        for (int ch = 127; ch >= 0; --ch) {
            int k = ch * 64 + lane;
            float e = expf(s1s[k]);
            float v = (c < 64) ? e * hT[perm[k]] : e;
#pragma unroll
            for (int o = 1; o < 64; o <<= 1) {
                float tv = __shfl_down(v, o);
                if (lane + o < 64) v += tv;
            }
            v += carry;
            if (c < 64) SufEH[(size_t)k * 64 + c] = v; else SufE[k] = v;
            carry = __shfl(v, 0);
        }
    } else {
        float carry = 0.f;
        for (int ch = 0; ch < 128; ++ch) {
            int k = ch * 64 + lane;
            float e = expf(0.01f * s1s[k]);
            float term = (c < 64) ? e * hT[perm[k]] : e;
            float v = term;
#pragma unroll
            for (int o = 1; o < 64; o <<= 1) {
                float tv = __shfl_up(v, o);
                if (lane >= o) v += tv;
            }
            float excl = v - term + carry;
            if (c < 64) PreEH[(size_t)k * 64 + c] = excl; else PreE[k] = excl;
            carry += __shfl(v, 63);
        }
        if (lane == 0) { if (c < 64) PreEH[8192 * 64 + c] = carry; else PreE[8192] = carry; }
    }
}

// ---------------------------------------------------------------------------
// K5: per row: binary-search split, combine branch sums -> h_att, +hidden,
// fc + leaky, out dot. 4 rows/block.
// ---------------------------------------------------------------------------
__global__ __launch_bounds__(256)
void finalize(const float* __restrict__ hidden, const float* __restrict__ s1s,
              const float* __restrict__ s2v,
              const float* __restrict__ SufE, const float* __restrict__ SufEH,
              const float* __restrict__ PreE, const float* __restrict__ PreEH,
              const float* __restrict__ fcW, const float* __restrict__ fcb,
              const float* __restrict__ outW, const float* __restrict__ outb,
              float* __restrict__ out)
{
    __shared__ float fcWT[64 * 64];
    __shared__ float h2[4][64];
    int tid = threadIdx.x, c = tid & 63, rw = tid >> 6;
    for (int i = tid; i < 4096; i += 256) fcWT[i] = fcW[(i & 63) * 64 + (i >> 6)];
    int row = blockIdx.x * 4 + rw;
    float s2 = s2v[row];
    float th = -s2;
    int lo = 0, hi = 8192;
    while (lo < hi) { int mid = (lo + hi) >> 1; if (s1s[mid] > th) hi = mid; else lo = mid + 1; }
    int k = lo;
    float ep = expf(s2);
    float en = expf(0.01f * s2);
    float den = ep * SufE[k] + en * PreE[k];
    float num = ep * SufEH[(size_t)k * 64 + c] + en * PreEH[(size_t)k * 64 + c];
    h2[rw][c] = num / den + hidden[(size_t)row * 64 + c];
    __syncthreads();
    float y = fcb[c];
    for (int u = 0; u < 64; ++u) y += fcWT[u * 64 + c] * h2[rw][u];
    y = y > 0.f ? y : 0.01f * y;
    float o = y * outW[c];
#pragma unroll
    for (int s = 32; s; s >>= 1) o += __shfl_xor(o, s);
    if (c == 0) out[row] = o + outb[0];
}

extern "C" void kernel_launch(void* const* d_in, const int* in_sizes, int n_in,
                              void* d_out, int out_size, void* d_ws, size_t ws_size,
                              hipStream_t stream)
{
    const float* x     = (const float*)d_in[0];
    const float* Wih0  = (const float*)d_in[1];
    const float* Whh0  = (const float*)d_in[2];
    const float* bih0  = (const float*)d_in[3];
    const float* bhh0  = (const float*)d_in[4];
    const float* Wih1  = (const float*)d_in[5];
    const float* Whh1  = (const float*)d_in[6];
    const float* bih1  = (const float*)d_in[7];
    const float* bhh1  = (const float*)d_in[8];
    const float* tW    = (const float*)d_in[9];
    const float* tb    = (const float*)d_in[10];
    const float* a     = (const float*)d_in[11];
    const float* fcW   = (const float*)d_in[12];
    const float* fcb   = (const float*)d_in[13];
    const float* outW  = (const float*)d_in[14];
    const float* outb  = (const float*)d_in[15];

    float* ws      = (float*)d_ws;
    float* hidden  = ws;                        // 8192*64
    float* s1      = hidden + 8192 * 64;        // 8192
    float* s2      = s1 + 8192;                 // 8192
    float* s1s     = s2 + 8192;                 // 8192
    int*   perm    = (int*)(s1s + 8192);        // 8192
    float* SufE    = (float*)(perm + 8192);     // 8200 (8193 used)
    float* PreE    = SufE + 8200;               // 8200
    float* SufEH   = PreE + 8200;               // 8193*64
    float* PreEH   = SufEH + 8193 * 64;         // 8193*64
    float* hiddenT = PreEH + 8193 * 64;         // 64*8192

    hipStreamCaptureStatus cap = hipStreamCaptureStatusNone;
    hipStreamIsCapturing(stream, &cap);
    if (cap == hipStreamCaptureStatusNone) {
        hipFuncSetAttribute(reinterpret_cast<const void*>(gru_fused),
                            hipFuncAttributeMaxDynamicSharedMemorySize, 163840);
        hipFuncSetAttribute(reinterpret_cast<const void*>(sort_s1),
                            hipFuncAttributeMaxDynamicSharedMemorySize, 65536);
    }

    gru_fused<<<256, 512, 163840, stream>>>(x, Wih0, Whh0, bih0, bhh0,
                                            Wih1, Whh1, bih1, bhh1, hidden);
    transposeH<<<128, 256, 0, stream>>>(hidden, hiddenT);
    attn_prep<<<2048, 256, 0, stream>>>(hidden, tW, tb, a, s1, s2);
    sort_s1<<<1, 1024, 65536, stream>>>(s1, s1s, perm);
    scans<<<130, 64, 0, stream>>>(s1s, perm, hiddenT, SufE, SufEH, PreE, PreEH);
    finalize<<<2048, 256, 0, stream>>>(hidden, s1s, s2, SufE, SufEH, PreE, PreEH,
                                       fcW, fcb, outW, outb, (float*)d_out);
}

// Round 5
// 433.149 us; speedup vs baseline: 3.5069x; 1.1158x over previous
//
#include <hip/hip_runtime.h>
#include <hip/hip_bf16.h>
#include <math.h>

#define TSTEPS 60
#define DIN 6

typedef __attribute__((ext_vector_type(8))) short short8v;
typedef __attribute__((ext_vector_type(4))) float f32x4;
#define MFMA16 __builtin_amdgcn_mfma_f32_16x16x32_bf16

__device__ __forceinline__ float fast_rcp(float x) { return __builtin_amdgcn_rcpf(x); }
__device__ __forceinline__ float sigf(float x) { return fast_rcp(1.0f + __expf(-x)); }
__device__ __forceinline__ float tanhf_(float x) {
    return 1.0f - 2.0f * fast_rcp(__expf(2.0f * x) + 1.0f);
}
__device__ __forceinline__ unsigned short f2bf(float f) {   // RTN-even
    unsigned u = __float_as_uint(f);
    u += 0x7fff + ((u >> 16) & 1);
    return (unsigned short)(u >> 16);
}
__device__ __forceinline__ float bf2f(unsigned short s) {
    return __uint_as_float(((unsigned)s) << 16);
}

// ---------------------------------------------------------------------------
// K1: fused 2-layer GRU, 60 steps, MFMA split-bf16 (hi+lo, 3-term) matmuls.
// (unchanged from round 4 — 180 us, MfmaUtil 25%)
// ---------------------------------------------------------------------------
__global__ __launch_bounds__(512, 1)
void gru_fused(const float* __restrict__ x,
               const float* __restrict__ Wih0, const float* __restrict__ Whh0,
               const float* __restrict__ bih0, const float* __restrict__ bhh0,
               const float* __restrict__ Wih1, const float* __restrict__ Whh1,
               const float* __restrict__ bih1, const float* __restrict__ bhh1,
               float* __restrict__ hidden)
{
    extern __shared__ char ldsb[];
    const int W0H = 0, W0L = 24576, W1IH = 49152, W1IL = 73728,
              W1HH = 98304, W1HL = 122880, HP = 147456;

    const int tid = threadIdx.x;
    const int l   = tid & 63;
    const int w   = tid >> 6;
    const int mt  = w >> 2;
    const int ur  = w & 3;
    const int l15 = l & 15;
    const int kb  = l >> 4;
    const int u_m = ur * 16 + l15;
    const int n0  = blockIdx.x * 32;

    for (int i = tid; i < 12288; i += 512) {
        int u = i >> 6, j = i & 63;
        int off = u * 128 + (((j >> 3) ^ (u & 7)) << 4) + (j & 7) * 2;
        float w0 = Whh0[i], w1 = Wih1[i], w2 = Whh1[i];
        unsigned short h0 = f2bf(w0); unsigned short l0 = f2bf(w0 - bf2f(h0));
        unsigned short h1 = f2bf(w1); unsigned short l1 = f2bf(w1 - bf2f(h1));
        unsigned short h2 = f2bf(w2); unsigned short l2 = f2bf(w2 - bf2f(h2));
        *(unsigned short*)(ldsb + W0H  + off) = h0;
        *(unsigned short*)(ldsb + W0L  + off) = l0;
        *(unsigned short*)(ldsb + W1IH + off) = h1;
        *(unsigned short*)(ldsb + W1IL + off) = l1;
        *(unsigned short*)(ldsb + W1HH + off) = h2;
        *(unsigned short*)(ldsb + W1HL + off) = l2;
    }
    for (int i = tid; i < 4096; i += 512) *(unsigned*)(ldsb + HP + i * 4) = 0u;

    float brz0_r = bih0[u_m] + bhh0[u_m];
    float brz0_z = bih0[64 + u_m] + bhh0[64 + u_m];
    float bi0n = bih0[128 + u_m], bh0n = bhh0[128 + u_m];
    float brz1_r = bih1[u_m] + bhh1[u_m];
    float brz1_z = bih1[64 + u_m] + bhh1[64 + u_m];
    float bi1n = bih1[128 + u_m], bh1n = bhh1[128 + u_m];

    float Wx[3][DIN];
#pragma unroll
    for (int g = 0; g < 3; ++g)
#pragma unroll
        for (int d = 0; d < DIN; ++d) Wx[g][d] = Wih0[(g * 64 + u_m) * DIN + d];

    const int rowA = mt * 16 + l15;
    const int bA0 = HP + rowA * 128 + ((kb ^ (rowA & 7)) << 4);
    const int bA1 = bA0 ^ 64;
    const int bB0 = u_m * 128 + ((kb ^ (u_m & 7)) << 4);
    const int bB1 = bB0 ^ 64;
    int wAo[4];
#pragma unroll
    for (int i = 0; i < 4; ++i) {
        int r = mt * 16 + kb * 4 + i;
        wAo[i] = HP + r * 128 + ((((u_m >> 3) & 7) ^ (r & 7)) << 4) + (u_m & 7) * 2;
    }
    const float* xp[4];
#pragma unroll
    for (int i = 0; i < 4; ++i)
        xp[i] = x + (size_t)(n0 + mt * 16 + kb * 4 + i) * (DIN * TSTEPS);

    float h0f[4] = {0.f, 0.f, 0.f, 0.f};
    float h1f[4] = {0.f, 0.f, 0.f, 0.f};

    __syncthreads();

#define LD8(o) (*(const short8v*)(ldsb + (o)))

    short8v B0[3][2][2];
#pragma unroll
    for (int g = 0; g < 3; ++g) {
        B0[g][0][0] = LD8(W0H + g * 8192 + bB0);
        B0[g][0][1] = LD8(W0H + g * 8192 + bB1);
        B0[g][1][0] = LD8(W0L + g * 8192 + bB0);
        B0[g][1][1] = LD8(W0L + g * 8192 + bB1);
    }

#pragma unroll 1
    for (int t = 0; t < TSTEPS; ++t) {
        float xv[4][DIN];
#pragma unroll
        for (int i = 0; i < 4; ++i)
#pragma unroll
            for (int d = 0; d < DIN; ++d) xv[i][d] = xp[i][d * TSTEPS + t];

        short8v aH0[2][2], aH1[2][2];
        aH0[0][0] = LD8(bA0);        aH0[1][0] = LD8(bA1);
        aH0[0][1] = LD8(bA0 + 4096); aH0[1][1] = LD8(bA1 + 4096);
        aH1[0][0] = LD8(bA0 + 8192); aH1[1][0] = LD8(bA1 + 8192);
        aH1[0][1] = LD8(bA0 + 12288); aH1[1][1] = LD8(bA1 + 12288);

        float gi0[4], gi1[4], gi2[4];
#pragma unroll
        for (int i = 0; i < 4; ++i) {
            float s0 = 0.f, s1 = 0.f, s2 = 0.f;
#pragma unroll
            for (int d = 0; d < DIN; ++d) {
                float xd = xv[i][d];
                s0 = fmaf(Wx[0][d], xd, s0);
                s1 = fmaf(Wx[1][d], xd, s1);
                s2 = fmaf(Wx[2][d], xd, s2);
            }
            gi0[i] = s0; gi1[i] = s1; gi2[i] = s2;
        }

        f32x4 Cr, Cz, Cnh;
#pragma unroll
        for (int i = 0; i < 4; ++i) {
            Cr[i] = brz0_r + gi0[i]; Cz[i] = brz0_z + gi1[i]; Cnh[i] = bh0n;
        }
        Cr = MFMA16(aH0[0][0], B0[0][0][0], Cr, 0, 0, 0);
        Cr = MFMA16(aH0[1][0], B0[0][0][1], Cr, 0, 0, 0);
        Cr = MFMA16(aH0[0][1], B0[0][0][0], Cr, 0, 0, 0);
        Cr = MFMA16(aH0[1][1], B0[0][0][1], Cr, 0, 0, 0);
        Cr = MFMA16(aH0[0][0], B0[0][1][0], Cr, 0, 0, 0);
        Cr = MFMA16(aH0[1][0], B0[0][1][1], Cr, 0, 0, 0);
        Cz = MFMA16(aH0[0][0], B0[1][0][0], Cz, 0, 0, 0);
        Cz = MFMA16(aH0[1][0], B0[1][0][1], Cz, 0, 0, 0);
        Cz = MFMA16(aH0[0][1], B0[1][0][0], Cz, 0, 0, 0);
        Cz = MFMA16(aH0[1][1], B0[1][0][1], Cz, 0, 0, 0);
        Cz = MFMA16(aH0[0][0], B0[1][1][0], Cz, 0, 0, 0);
        Cz = MFMA16(aH0[1][0], B0[1][1][1], Cz, 0, 0, 0);
        Cnh = MFMA16(aH0[0][0], B0[2][0][0], Cnh, 0, 0, 0);
        Cnh = MFMA16(aH0[1][0], B0[2][0][1], Cnh, 0, 0, 0);
        Cnh = MFMA16(aH0[0][1], B0[2][0][0], Cnh, 0, 0, 0);
        Cnh = MFMA16(aH0[1][1], B0[2][0][1], Cnh, 0, 0, 0);
        Cnh = MFMA16(aH0[0][0], B0[2][1][0], Cnh, 0, 0, 0);
        Cnh = MFMA16(aH0[1][0], B0[2][1][1], Cnh, 0, 0, 0);

        unsigned short hh[4], hl[4];
#pragma unroll
        for (int i = 0; i < 4; ++i) {
            float r = sigf(Cr[i]);
            float z = sigf(Cz[i]);
            float n = tanhf_(gi2[i] + bi0n + r * Cnh[i]);
            h0f[i] = (1.f - z) * n + z * h0f[i];
            hh[i] = f2bf(h0f[i]);
            hl[i] = f2bf(h0f[i] - bf2f(hh[i]));
        }
        __syncthreads();
#pragma unroll
        for (int i = 0; i < 4; ++i) {
            *(unsigned short*)(ldsb + wAo[i]) = hh[i];
            *(unsigned short*)(ldsb + wAo[i] + 4096) = hl[i];
        }
        __syncthreads();

        short8v aN[2][2];
        aN[0][0] = LD8(bA0);        aN[1][0] = LD8(bA1);
        aN[0][1] = LD8(bA0 + 4096); aN[1][1] = LD8(bA1 + 4096);

        f32x4 Dr, Dz, Dni, Dnh;
#pragma unroll
        for (int i = 0; i < 4; ++i) {
            Dr[i] = brz1_r; Dz[i] = brz1_z; Dni[i] = bi1n; Dnh[i] = bh1n;
        }
        {
            short8v bih_ = LD8(W1IH + bB0), bih1_ = LD8(W1IH + bB1);
            short8v bil_ = LD8(W1IL + bB0), bil1_ = LD8(W1IL + bB1);
            Dr = MFMA16(aN[0][0], bih_, Dr, 0, 0, 0);
            Dr = MFMA16(aN[1][0], bih1_, Dr, 0, 0, 0);
            Dr = MFMA16(aN[0][1], bih_, Dr, 0, 0, 0);
            Dr = MFMA16(aN[1][1], bih1_, Dr, 0, 0, 0);
            Dr = MFMA16(aN[0][0], bil_, Dr, 0, 0, 0);
            Dr = MFMA16(aN[1][0], bil1_, Dr, 0, 0, 0);
            short8v bhh_ = LD8(W1HH + bB0), bhh1_ = LD8(W1HH + bB1);
            short8v bhl_ = LD8(W1HL + bB0), bhl1_ = LD8(W1HL + bB1);
            Dr = MFMA16(aH1[0][0], bhh_, Dr, 0, 0, 0);
            Dr = MFMA16(aH1[1][0], bhh1_, Dr, 0, 0, 0);
            Dr = MFMA16(aH1[0][1], bhh_, Dr, 0, 0, 0);
            Dr = MFMA16(aH1[1][1], bhh1_, Dr, 0, 0, 0);
            Dr = MFMA16(aH1[0][0], bhl_, Dr, 0, 0, 0);
            Dr = MFMA16(aH1[1][0], bhl1_, Dr, 0, 0, 0);
        }
        {
            short8v bih_ = LD8(W1IH + 8192 + bB0), bih1_ = LD8(W1IH + 8192 + bB1);
            short8v bil_ = LD8(W1IL + 8192 + bB0), bil1_ = LD8(W1IL + 8192 + bB1);
            Dz = MFMA16(aN[0][0], bih_, Dz, 0, 0, 0);
            Dz = MFMA16(aN[1][0], bih1_, Dz, 0, 0, 0);
            Dz = MFMA16(aN[0][1], bih_, Dz, 0, 0, 0);
            Dz = MFMA16(aN[1][1], bih1_, Dz, 0, 0, 0);
            Dz = MFMA16(aN[0][0], bil_, Dz, 0, 0, 0);
            Dz = MFMA16(aN[1][0], bil1_, Dz, 0, 0, 0);
            short8v bhh_ = LD8(W1HH + 8192 + bB0), bhh1_ = LD8(W1HH + 8192 + bB1);
            short8v bhl_ = LD8(W1HL + 8192 + bB0), bhl1_ = LD8(W1HL + 8192 + bB1);
            Dz = MFMA16(aH1[0][0], bhh_, Dz, 0, 0, 0);
            Dz = MFMA16(aH1[1][0], bhh1_, Dz, 0, 0, 0);
            Dz = MFMA16(aH1[0][1], bhh_, Dz, 0, 0, 0);
            Dz = MFMA16(aH1[1][1], bhh1_, Dz, 0, 0, 0);
            Dz = MFMA16(aH1[0][0], bhl_, Dz, 0, 0, 0);
            Dz = MFMA16(aH1[1][0], bhl1_, Dz, 0, 0, 0);
        }
        {
            short8v bih_ = LD8(W1IH + 16384 + bB0), bih1_ = LD8(W1IH + 16384 + bB1);
            short8v bil_ = LD8(W1IL + 16384 + bB0), bil1_ = LD8(W1IL + 16384 + bB1);
            Dni = MFMA16(aN[0][0], bih_, Dni, 0, 0, 0);
            Dni = MFMA16(aN[1][0], bih1_, Dni, 0, 0, 0);
            Dni = MFMA16(aN[0][1], bih_, Dni, 0, 0, 0);
            Dni = MFMA16(aN[1][1], bih1_, Dni, 0, 0, 0);
            Dni = MFMA16(aN[0][0], bil_, Dni, 0, 0, 0);
            Dni = MFMA16(aN[1][0], bil1_, Dni, 0, 0, 0);
            short8v bhh_ = LD8(W1HH + 16384 + bB0), bhh1_ = LD8(W1HH + 16384 + bB1);
            short8v bhl_ = LD8(W1HL + 16384 + bB0), bhl1_ = LD8(W1HL + 16384 + bB1);
            Dnh = MFMA16(aH1[0][0], bhh_, Dnh, 0, 0, 0);
            Dnh = MFMA16(aH1[1][0], bhh1_, Dnh, 0, 0, 0);
            Dnh = MFMA16(aH1[0][1], bhh_, Dnh, 0, 0, 0);
            Dnh = MFMA16(aH1[1][1], bhh1_, Dnh, 0, 0, 0);
            Dnh = MFMA16(aH1[0][0], bhl_, Dnh, 0, 0, 0);
            Dnh = MFMA16(aH1[1][0], bhl1_, Dnh, 0, 0, 0);
        }
#pragma unroll
        for (int i = 0; i < 4; ++i) {
            float r = sigf(Dr[i]);
            float z = sigf(Dz[i]);
            float n = tanhf_(Dni[i] + r * Dnh[i]);
            h1f[i] = (1.f - z) * n + z * h1f[i];
            unsigned short hhi = f2bf(h1f[i]);
            *(unsigned short*)(ldsb + wAo[i] + 8192) = hhi;
            *(unsigned short*)(ldsb + wAo[i] + 12288) = f2bf(h1f[i] - bf2f(hhi));
        }
        __syncthreads();
    }

#pragma unroll
    for (int i = 0; i < 4; ++i)
        hidden[(size_t)(n0 + mt * 16 + kb * 4 + i) * 64 + u_m] = h1f[i];
#undef LD8
}

// ---------------------------------------------------------------------------
// K2: t = hidden @ tW.T + tb ; s1 = t@a1 ; s2 = t@a2 ; + exp branch tables.
// ---------------------------------------------------------------------------
__global__ __launch_bounds__(256)
void attn_prep(const float* __restrict__ hidden, const float* __restrict__ tW,
               const float* __restrict__ tb, const float* __restrict__ a,
               float* __restrict__ s1, float* __restrict__ s2,
               float* __restrict__ E1p, float* __restrict__ E1n,
               float* __restrict__ E2p, float* __restrict__ E2n)
{
    __shared__ float WT[64 * 64];
    __shared__ float hrow[4][64];
    int tid = threadIdx.x, c = tid & 63, rw = tid >> 6;
    for (int i = tid; i < 4096; i += 256) WT[i] = tW[(i & 63) * 64 + (i >> 6)];
    int row = blockIdx.x * 4 + rw;
    hrow[rw][c] = hidden[(size_t)row * 64 + c];
    __syncthreads();
    float tc = tb[c];
    for (int u = 0; u < 64; ++u) tc += WT[u * 64 + c] * hrow[rw][u];
    float p1 = tc * a[c], p2 = tc * a[64 + c];
#pragma unroll
    for (int o = 32; o; o >>= 1) { p1 += __shfl_xor(p1, o); p2 += __shfl_xor(p2, o); }
    if (c == 0) {
        s1[row] = p1; s2[row] = p2;
        E1p[row] = expf(p1); E1n[row] = expf(0.01f * p1);
        E2p[row] = expf(p2); E2n[row] = expf(0.01f * p2);
    }
}

// ---------------------------------------------------------------------------
// K3: hiT planes: hiT_{hi,lo}[c][j] = split-bf16 of hidden[j][c].
// 128 blocks x 64 rows; LDS-transposed, coalesced reads, 16B stores.
// ---------------------------------------------------------------------------
__global__ __launch_bounds__(256)
void transposeHbf(const float* __restrict__ hidden,
                  unsigned short* __restrict__ hiTh, unsigned short* __restrict__ hiTl)
{
    __shared__ float tile[64][65];
    int b = blockIdx.x, tid = threadIdx.x;
    for (int i = tid; i < 4096; i += 256) {
        int r = i >> 6, c = i & 63;
        tile[c][r] = hidden[(size_t)(b * 64 + r) * 64 + c];
    }
    __syncthreads();
    int c = tid & 63, seg = tid >> 6;
    unsigned short oh[16], ol[16];
#pragma unroll
    for (int k = 0; k < 16; ++k) {
        float v = tile[c][seg * 16 + k];
        unsigned short h = f2bf(v);
        oh[k] = h; ol[k] = f2bf(v - bf2f(h));
    }
    size_t base = (size_t)c * 8192 + b * 64 + seg * 16;
    *(short8v*)(hiTh + base)     = *(const short8v*)(oh);
    *(short8v*)(hiTh + base + 8) = *(const short8v*)(oh + 8);
    *(short8v*)(hiTl + base)     = *(const short8v*)(ol);
    *(short8v*)(hiTl + base + 8) = *(const short8v*)(ol + 8);
}

// ---------------------------------------------------------------------------
// K4: flash attention via rank-1 branch decomposition (no per-pair exp):
// e_ij = (s2_i+s1_j>0) ? E1p[j]*E2p[i] : E1n[j]*E2n[i].
// 256 blocks x 4 waves; wave (iw,jh) = 16 rows x 4096-j half; A=e split-bf16
// built in-register, B frags loaded straight from hiT planes (L2-resident),
// 3-term MFMA; den in exact fp32. Pair-combine via LDS; h2 = num/den + hidden.
// ---------------------------------------------------------------------------
__global__ __launch_bounds__(256)
void flash_attn(const float* __restrict__ s1, const float* __restrict__ s2,
                const float* __restrict__ E1p, const float* __restrict__ E1n,
                const float* __restrict__ E2p, const float* __restrict__ E2n,
                const unsigned short* __restrict__ hiTh,
                const unsigned short* __restrict__ hiTl,
                const float* __restrict__ hidden, float* __restrict__ h2)
{
    __shared__ float comb[4][64][17];
    const int tid = threadIdx.x;
    const int l = tid & 63, w = tid >> 6;
    const int iw = w >> 1, jh = w & 1;
    const int l15 = l & 15, kb = l >> 4;
    const int i0 = blockIdx.x * 32 + iw * 16;

    const float s2i  = s2[i0 + l15];
    const float E2pv = E2p[i0 + l15];
    const float E2nv = E2n[i0 + l15];

    f32x4 C[4];
#pragma unroll
    for (int ct = 0; ct < 4; ++ct)
#pragma unroll
        for (int r = 0; r < 4; ++r) C[ct][r] = 0.f;
    float den = 0.f;

#pragma unroll 2
    for (int it = 0; it < 128; ++it) {
        const int jk = jh * 4096 + it * 32 + kb * 8;
        float4 s1a = *(const float4*)(s1 + jk);
        float4 s1b = *(const float4*)(s1 + jk + 4);
        float4 p1a = *(const float4*)(E1p + jk);
        float4 p1b = *(const float4*)(E1p + jk + 4);
        float4 n1a = *(const float4*)(E1n + jk);
        float4 n1b = *(const float4*)(E1n + jk + 4);

        short8v Bh[4], Bl[4];
#pragma unroll
        for (int ct = 0; ct < 4; ++ct) {
            size_t off = (size_t)(ct * 16 + l15) * 8192 + jk;
            Bh[ct] = *(const short8v*)(hiTh + off);
            Bl[ct] = *(const short8v*)(hiTl + off);
        }

        unsigned short ah[8], al[8];
#define MK(e, sv, pv, nv)                                            \
        {                                                            \
            float s = s2i + (sv);                                    \
            bool cpos = s > 0.f;                                     \
            float w1 = cpos ? (pv) : (nv);                           \
            float w2 = cpos ? E2pv : E2nv;                           \
            float ev = w1 * w2;                                      \
            den += ev;                                               \
            unsigned short hx = f2bf(ev);                            \
            ah[e] = hx; al[e] = f2bf(ev - bf2f(hx));                 \
        }
        MK(0, s1a.x, p1a.x, n1a.x) MK(1, s1a.y, p1a.y, n1a.y)
        MK(2, s1a.z, p1a.z, n1a.z) MK(3, s1a.w, p1a.w, n1a.w)
        MK(4, s1b.x, p1b.x, n1b.x) MK(5, s1b.y, p1b.y, n1b.y)
        MK(6, s1b.z, p1b.z, n1b.z) MK(7, s1b.w, p1b.w, n1b.w)
#undef MK
        short8v Ah = { (short)ah[0], (short)ah[1], (short)ah[2], (short)ah[3],
                       (short)ah[4], (short)ah[5], (short)ah[6], (short)ah[7] };
        short8v Al = { (short)al[0], (short)al[1], (short)al[2], (short)al[3],
                       (short)al[4], (short)al[5], (short)al[6], (short)al[7] };

#pragma unroll
        for (int ct = 0; ct < 4; ++ct) {
            C[ct] = MFMA16(Ah, Bh[ct], C[ct], 0, 0, 0);
            C[ct] = MFMA16(Al, Bh[ct], C[ct], 0, 0, 0);
            C[ct] = MFMA16(Ah, Bl[ct], C[ct], 0, 0, 0);
        }
    }

    // den: sum over kb groups -> all lanes hold den(row=l15) for this j-half
    den += __shfl_xor(den, 16);
    den += __shfl_xor(den, 32);

#pragma unroll
    for (int ct = 0; ct < 4; ++ct)
#pragma unroll
        for (int r = 0; r < 4; ++r) comb[w][l][ct * 4 + r] = C[ct][r];
    comb[w][l][16] = den;
    __syncthreads();

    if (jh == 0) {
        float den_t = comb[w][l][16] + comb[w + 1][l][16];
#pragma unroll
        for (int ct = 0; ct < 4; ++ct) {
#pragma unroll
            for (int r = 0; r < 4; ++r) {
                int rr = kb * 4 + r;
                float num = comb[w][l][ct * 4 + r] + comb[w + 1][l][ct * 4 + r];
                float dv = __shfl(den_t, rr);
                size_t oidx = (size_t)(i0 + rr) * 64 + ct * 16 + l15;
                h2[oidx] = num / dv + hidden[oidx];
            }
        }
    }
}

// ---------------------------------------------------------------------------
// K5: h = leaky(h2 @ fcW.T + fcb) ; out = h @ outW.T + outb.  4 rows/block.
// ---------------------------------------------------------------------------
__global__ __launch_bounds__(256)
void fc_out(const float* __restrict__ h2,
            const float* __restrict__ fcW, const float* __restrict__ fcb,
            const float* __restrict__ outW, const float* __restrict__ outb,
            float* __restrict__ out)
{
    __shared__ float fcWT[64 * 64];
    __shared__ float hrow[4][64];
    int tid = threadIdx.x, c = tid & 63, rw = tid >> 6;
    for (int i = tid; i < 4096; i += 256) fcWT[i] = fcW[(i & 63) * 64 + (i >> 6)];
    int row = blockIdx.x * 4 + rw;
    hrow[rw][c] = h2[(size_t)row * 64 + c];
    __syncthreads();
    float y = fcb[c];
    for (int u = 0; u < 64; ++u) y += fcWT[u * 64 + c] * hrow[rw][u];
    y = y > 0.f ? y : 0.01f * y;
    float o = y * outW[c];
#pragma unroll
    for (int s = 32; s; s >>= 1) o += __shfl_xor(o, s);
    if (c == 0) out[row] = o + outb[0];
}

extern "C" void kernel_launch(void* const* d_in, const int* in_sizes, int n_in,
                              void* d_out, int out_size, void* d_ws, size_t ws_size,
                              hipStream_t stream)
{
    const float* x     = (const float*)d_in[0];
    const float* Wih0  = (const float*)d_in[1];
    const float* Whh0  = (const float*)d_in[2];
    const float* bih0  = (const float*)d_in[3];
    const float* bhh0  = (const float*)d_in[4];
    const float* Wih1  = (const float*)d_in[5];
    const float* Whh1  = (const float*)d_in[6];
    const float* bih1  = (const float*)d_in[7];
    const float* bhh1  = (const float*)d_in[8];
    const float* tW    = (const float*)d_in[9];
    const float* tb    = (const float*)d_in[10];
    const float* a     = (const float*)d_in[11];
    const float* fcW   = (const float*)d_in[12];
    const float* fcb   = (const float*)d_in[13];
    const float* outW  = (const float*)d_in[14];
    const float* outb  = (const float*)d_in[15];

    float* ws      = (float*)d_ws;
    float* hidden  = ws;                          // 8192*64        (524288)
    float* s1      = hidden + 524288;             // 8192
    float* s2      = s1 + 8192;
    float* E1p     = s2 + 8192;
    float* E1n     = E1p + 8192;
    float* E2p     = E1n + 8192;
    float* E2n     = E2p + 8192;                  // ends at 573440 floats
    unsigned short* hiTh = (unsigned short*)(ws + 573440);   // 8192*64 u16
    unsigned short* hiTl = hiTh + 524288;                    // 8192*64 u16
    float* h2      = ws + 573440 + 524288;        // 8192*64 f32

    hipStreamCaptureStatus cap = hipStreamCaptureStatusNone;
    hipStreamIsCapturing(stream, &cap);
    if (cap == hipStreamCaptureStatusNone) {
        hipFuncSetAttribute(reinterpret_cast<const void*>(gru_fused),
                            hipFuncAttributeMaxDynamicSharedMemorySize, 163840);
    }

    gru_fused<<<256, 512, 163840, stream>>>(x, Wih0, Whh0, bih0, bhh0,
                                            Wih1, Whh1, bih1, bhh1, hidden);
    attn_prep<<<2048, 256, 0, stream>>>(hidden, tW, tb, a, s1, s2,
                                        E1p, E1n, E2p, E2n);
    transposeHbf<<<128, 256, 0, stream>>>(hidden, hiTh, hiTl);
    flash_attn<<<256, 256, 0, stream>>>(s1, s2, E1p, E1n, E2p, E2n,
                                        hiTh, hiTl, hidden, h2);
    fc_out<<<2048, 256, 0, stream>>>(h2, fcW, fcb, outW, outb, (float*)d_out);
}